// Round 7
// baseline (262.604 us; speedup 1.0000x reference)
//
#include <hip/hip_runtime.h>
#include <math.h>

// InteractionGate: N=500000 agents, H=64, D=32.
// Reduction: d1 == 0 always; d2[i] = ||goal[i]-position[i]||;
// new_h[i][j] = sigmoid(C[j] + d2[i]*Wd[j] + dot(h[i], W2[j][:])), W2[j][k]=W_fc[j][64+k].
// h_out[idx] = h[idx]. goal_out (64) computed once.
//
// R11: remove the store->load serialization present in EVERY config R4-R10.
// The masked `if (agent==idx) vv = load h[row]` inside the store loop made
// each store depend on a just-issued global load; in-order vmcnt means the
// compiler's wait before the store covers the NEWEST VMEM op -> vmcnt(0) ->
// full drain of all prefetch loads + stores, every iteration. That floor
// explains the 8-config invariant (3.0-3.3 TB/s fabric regardless of depth/
// occupancy/shape). Fix with zero common-path cost: for the one tile that
// contains idx, the needed output bytes (h[idx] row) are ALREADY in the
// staged registers G_k -- so delete the masked loads and, on a wave-uniform
// branch (mt == idx>>4, 1 wave in 8192), blend S_k from G_k with a cndmask.
// Stores now depend on no VMEM op; the depth-1 pipeline overlaps at last.
// Everything else identical to R10 (dense transactions, LDS redistribution,
// chunk-XOR swizzle, boustrophedon, shared row-0 clamp).

#define AH 64
#define AD 32

typedef __attribute__((ext_vector_type(8))) short bf16x8;
typedef __attribute__((ext_vector_type(4))) float f32x4;
typedef __attribute__((ext_vector_type(2))) float f32x2;

__device__ __forceinline__ float sigmoid_fast(float x) {
    return __builtin_amdgcn_rcpf(1.0f + __expf(-x));
}

__device__ __forceinline__ short f2bf(float f) {
    union { float f; unsigned u; } v; v.f = f;
    unsigned r = v.u + 0x7fffu + ((v.u >> 16) & 1u);
    return (short)(r >> 16);
}

// ws layout (floats): [0:64) C, [64:128) Wd, [128:2176) = bf16x8 wfrag[8][64],
// [2176] (as int) = launch counter for sweep direction.
__global__ void ig_precompute(
    const float* __restrict__ h,      // N x 64
    const float* __restrict__ ghs,    // 64
    const float* __restrict__ goal,   // N x 2
    const float* __restrict__ pos,    // N x 2
    const float* __restrict__ W_emb,  // 32 x 2
    const float* __restrict__ b_emb,  // 32
    const float* __restrict__ W_fc,   // 64 x 192
    const float* __restrict__ b_fc,   // 64
    const int*   __restrict__ idx_p,
    float* __restrict__ out_goal,     // 64
    float* __restrict__ ws,
    int*   flip)                      // may be null
{
    const int l = threadIdx.x;        // 0..63
    if (l >= 64) return;
    const int idx = idx_p[0];
    const int m15 = l & 15, q = l >> 4;

    if (l == 0 && flip) flip[0] = flip[0] + 1;   // alternates sweep direction

    // --- C[l], Wd[l], goal_out[l] ---
    const float* wrow = W_fc + l * 192;
    const f32x4* w4  = (const f32x4*)wrow;
    const f32x4* wg4 = (const f32x4*)(wrow + AH);
    const f32x4* h4  = (const f32x4*)(h + (size_t)idx * AH);
    const f32x4* g4  = (const f32x4*)ghs;
    float c = b_fc[l], g = b_fc[l];
    #pragma unroll
    for (int m = 0; m < 16; ++m) {
        const f32x4 hv = h4[m], wv = w4[m];
        const float d = hv[0]*wv[0] + hv[1]*wv[1] + hv[2]*wv[2] + hv[3]*wv[3];
        c += d; g += d;
        const f32x4 gv = g4[m], wv2 = wg4[m];
        g += gv[0]*wv2[0] + gv[1]*wv2[1] + gv[2]*wv2[2] + gv[3]*wv2[3];
    }
    const float px = pos[(size_t)idx*2+0], py = pos[(size_t)idx*2+1];
    const float gx = goal[(size_t)idx*2+0], gy = goal[(size_t)idx*2+1];
    const float dgx = px - gx, dgy = py - gy;
    const float dg = sqrtf(dgx*dgx + dgy*dgy);
    const float* wd1 = wrow + 128;
    const float* wd2 = wrow + 160;
    float wd = 0.f;
    #pragma unroll
    for (int k = 0; k < AD; ++k) {
        const float wsum = W_emb[2*k] + W_emb[2*k+1];
        const float be   = b_emb[k];
        const float w12  = wd1[k] + wd2[k];
        c  += be * w12;
        wd += wsum * wd2[k];
        g  += (dg * wsum + be) * w12;
    }
    ws[l]      = c;
    ws[64 + l] = wd;
    out_goal[l] = sigmoid_fast(g);

    // --- weight A-frags: wfrag[f=mg*2+cc][lane] = W2[mg*16+m15][cc*32+q*8 .. +7] ---
    bf16x8* wf = (bf16x8*)(ws + 128);
    #pragma unroll
    for (int f = 0; f < 8; ++f) {
        const int mg = f >> 1, cc = f & 1;
        const float* src = W_fc + (size_t)(mg*16 + m15) * 192 + AH + cc*32 + q*8;
        const f32x4 s0 = *(const f32x4*)(src);
        const f32x4 s1 = *(const f32x4*)(src + 4);
        bf16x8 b;
        #pragma unroll
        for (int j = 0; j < 4; ++j) { b[j] = f2bf(s0[j]); b[4+j] = f2bf(s1[j]); }
        wf[f * 64 + l] = b;
    }
}

__global__ __launch_bounds__(256, 4) void ig_main(
    const float* __restrict__ h,      // N x 64
    const float* __restrict__ goal,   // N x 2
    const float* __restrict__ pos,    // N x 2
    const float* __restrict__ ws,     // C, Wd, wfrag
    const int*   __restrict__ idx_p,
    const int*   __restrict__ flip,   // may be null
    float* __restrict__ out,          // N x 64
    int n_tiles, int total_waves)
{
    __shared__ bf16x8 wlds[8][64];               // 8 KB (weight frags)
    __shared__ __align__(16) float cw[128];      // C, Wd
    __shared__ __align__(16) float tbuf[4][1024];// per-wave 4KB tile buffer

    const int tid  = threadIdx.x;
    const int w    = tid >> 6;
    const int lane = tid & 63;
    const int m15  = lane & 15;
    const int q    = lane >> 4;
    const int idx  = idx_p[0];
    const int dir  = flip ? (flip[0] & 1) : 0;   // wave-uniform
    const int nt1  = n_tiles - 1;

    // idx-tile bookkeeping (wave-uniform scalars + one per-lane mask).
    const int idx_tile = idx >> 4;               // tile containing row idx
    const int idx_r    = idx & 15;               // row within that tile
    const int idx_k    = idx_r >> 2;             // register quarter holding it
    const bool idx_lane = ((lane >> 4) == (idx_r & 3)); // lanes covering the row

    // Stage ws -> LDS: 128 floats + 512 x 16B chunks.
    if (tid < 128) cw[tid] = ws[tid];
    {
        const f32x4* src = (const f32x4*)(ws + 128);
        f32x4* dst = (f32x4*)wlds;
        dst[tid]       = src[tid];
        dst[tid + 256] = src[tid + 256];
    }
    __syncthreads();

    float* tb = tbuf[w];                         // this wave's private buffer

    // Loop-invariant LDS float-offsets. Tile = 16 rows x 16 chunks (16B each);
    // chunk (r,c) lives at float offset (r*16 + (c ^ (r&7))) * 4.
    int stg0, stg1, stg2, stg3;
    {
        const int r0 = 0*4 + (lane >> 4), c = lane & 15;
        const int r1 = r0 + 4, r2 = r0 + 8, r3 = r0 + 12;
        stg0 = (r0*16 + (c ^ (r0 & 7))) * 4;
        stg1 = (r1*16 + (c ^ (r1 & 7))) * 4;
        stg2 = (r2*16 + (c ^ (r2 & 7))) * 4;
        stg3 = (r3*16 + (c ^ (r3 & 7))) * 4;
    }
    const int e = m15 & 7;
    // MFMA fragment chunks: row m15, chunks {2q,2q+1,8+2q,9+2q}.
    const int fb0 = (m15*16 + ((2*q)     ^ e)) * 4;
    const int fb1 = (m15*16 + ((2*q + 1) ^ e)) * 4;
    const int fb2 = (m15*16 + ((8 + 2*q) ^ e)) * 4;
    const int fb3 = (m15*16 + ((9 + 2*q) ^ e)) * 4;
    // Result chunks: row m15, chunk mg*4+q (floats mg*16+q*4 .. +3).
    const int ow0 = (m15*16 + ((0*4 + q) ^ e)) * 4;
    const int ow1 = (m15*16 + ((1*4 + q) ^ e)) * 4;
    const int ow2 = (m15*16 + ((2*4 + q) ^ e)) * 4;
    const int ow3 = (m15*16 + ((3*4 + q) ^ e)) * 4;

    const int wid = blockIdx.x * 4 + w;
    const int TW  = total_waves;                 // 4096

    // Depth-1 pipeline: tile t's 4KB is in regs G0..G3 (dense layout:
    // Gk = tile bytes [k*1024 + lane*16, +16) ), goal/pos in gv/pv.
    int t = wid;                                 // wid < 4096 <= n_tiles
    f32x4 G0, G1, G2, G3; f32x2 gv, pv;
    {
        const int mt = dir ? nt1 - t : t;
        const float* hb = h + (size_t)mt * 1024;
        G0 = *(const f32x4*)(hb +   0 + lane*4);
        G1 = *(const f32x4*)(hb + 256 + lane*4);
        G2 = *(const f32x4*)(hb + 512 + lane*4);
        G3 = *(const f32x4*)(hb + 768 + lane*4);
        const int nn = mt*16 + m15;
        gv = *(const f32x2*)(goal + 2*(size_t)nn);
        pv = *(const f32x2*)(pos  + 2*(size_t)nn);
    }

    while (t < n_tiles) {
        // Dense prefetch of next tile (shared row-0 clamp past end: one 4KB
        // region for ALL waves -> L2-hot, ~free). Issued before anything
        // else so later waitcnts never drain this iteration's stores.
        const int tn  = t + TW;
        const int mtn = (tn < n_tiles) ? (dir ? nt1 - tn : tn) : 0;
        f32x4 N0, N1, N2, N3; f32x2 ngv, npv;
        {
            const float* hb = h + (size_t)mtn * 1024;
            N0 = *(const f32x4*)(hb +   0 + lane*4);
            N1 = *(const f32x4*)(hb + 256 + lane*4);
            N2 = *(const f32x4*)(hb + 512 + lane*4);
            N3 = *(const f32x4*)(hb + 768 + lane*4);
            const int nn = mtn*16 + m15;
            ngv = *(const f32x2*)(goal + 2*(size_t)nn);
            npv = *(const f32x2*)(pos  + 2*(size_t)nn);
        }

        // Stage current tile into LDS (waits only on last iter's loads,
        // which have had a full iteration to complete).
        *(f32x4*)(tb + stg0) = G0;
        *(f32x4*)(tb + stg1) = G1;
        *(f32x4*)(tb + stg2) = G2;
        *(f32x4*)(tb + stg3) = G3;

        // Read MFMA fragments (in-order DS per wave; compiler inserts lgkm).
        const f32x4 b0 = *(const f32x4*)(tb + fb0);
        const f32x4 b1 = *(const f32x4*)(tb + fb1);
        const f32x4 b2 = *(const f32x4*)(tb + fb2);
        const f32x4 b3 = *(const f32x4*)(tb + fb3);

        const int mt = dir ? nt1 - t : t;
        const float dx = gv[0] - pv[0], dy = gv[1] - pv[1];
        const float d2v = sqrtf(dx*dx + dy*dy);

        bf16x8 bf0, bf1;
        #pragma unroll
        for (int j = 0; j < 4; ++j) {
            bf0[j] = f2bf(b0[j]); bf0[4+j] = f2bf(b1[j]);
            bf1[j] = f2bf(b2[j]); bf1[4+j] = f2bf(b3[j]);
        }

        #pragma unroll
        for (int mg = 0; mg < 4; ++mg) {
            const f32x4 c4 = *(const f32x4*)&cw[mg*16 + q*4];
            const f32x4 d4 = *(const f32x4*)&cw[64 + mg*16 + q*4];
            f32x4 acc;
            #pragma unroll
            for (int r = 0; r < 4; ++r) acc[r] = c4[r] + d2v * d4[r];
            acc = __builtin_amdgcn_mfma_f32_16x16x32_bf16(wlds[mg*2+0][lane], bf0, acc, 0, 0, 0);
            acc = __builtin_amdgcn_mfma_f32_16x16x32_bf16(wlds[mg*2+1][lane], bf1, acc, 0, 0, 0);

            f32x4 vv;
            #pragma unroll
            for (int r = 0; r < 4; ++r) vv[r] = sigmoid_fast(acc[r]);
            const int owx = (mg == 0) ? ow0 : (mg == 1) ? ow1 : (mg == 2) ? ow2 : ow3;
            *(f32x4*)(tb + owx) = vv;            // LDS result write (swizzled)
        }

        // Dense read-back.
        f32x4 S0 = *(const f32x4*)(tb + stg0);
        f32x4 S1 = *(const f32x4*)(tb + stg1);
        f32x4 S2 = *(const f32x4*)(tb + stg2);
        f32x4 S3 = *(const f32x4*)(tb + stg3);

        // h_out[idx] = h[idx]: the needed bytes are ALREADY in G_k for the
        // owning tile. Wave-uniform branch (taken by 1 wave in 8192), pure
        // VALU blend -- no loads, so stores keep zero VMEM dependencies.
        if (mt == idx_tile) {
            if (idx_lane) {
                if (idx_k == 0) S0 = G0;
                else if (idx_k == 1) S1 = G1;
                else if (idx_k == 2) S2 = G2;
                else S3 = G3;
            }
        }

        // Dense global store (full 128B lines per instruction).
        float* ob = out + (size_t)mt * 1024;
        *(f32x4*)(ob +   0 + lane*4) = S0;
        *(f32x4*)(ob + 256 + lane*4) = S1;
        *(f32x4*)(ob + 512 + lane*4) = S2;
        *(f32x4*)(ob + 768 + lane*4) = S3;

        t = tn;
        G0 = N0; G1 = N1; G2 = N2; G3 = N3; gv = ngv; pv = npv;
    }
}

extern "C" void kernel_launch(void* const* d_in, const int* in_sizes, int n_in,
                              void* d_out, int out_size, void* d_ws, size_t ws_size,
                              hipStream_t stream) {
    const float* h     = (const float*)d_in[0];
    const float* ghs   = (const float*)d_in[1];
    const float* goal  = (const float*)d_in[2];
    const float* pos   = (const float*)d_in[3];
    const float* W_emb = (const float*)d_in[4];
    const float* b_emb = (const float*)d_in[5];
    const float* W_fc  = (const float*)d_in[6];
    const float* b_fc  = (const float*)d_in[7];
    const int*   idx_p = (const int*)d_in[8];

    const int N = in_sizes[0] / AH;          // 500000
    float* out      = (float*)d_out;
    float* out_goal = out + (size_t)N * AH;
    float* ws       = (float*)d_ws;          // 128 + 2048 floats + counter
    int*   flip     = (ws_size >= 2177u * 4u) ? ((int*)d_ws) + 2176 : (int*)0;

    ig_precompute<<<1, 64, 0, stream>>>(h, ghs, goal, pos, W_emb, b_emb, W_fc, b_fc,
                                        idx_p, out_goal, ws, flip);

    const int n_tiles = N / 16;              // 31250
    const int blocks = 1024;                 // 4 blocks/CU (LDS 24.5KB/block)
    const int total_waves = blocks * 4;      // TW = 4096
    ig_main<<<blocks, 256, 0, stream>>>(h, goal, pos, ws, idx_p, flip, out,
                                        n_tiles, total_waves);
}

// Round 8
// 259.620 us; speedup vs baseline: 1.0115x; 1.0115x over previous
//
#include <hip/hip_runtime.h>
#include <math.h>

// InteractionGate: N=500000 agents, H=64, D=32.
// Reduction: d1 == 0 always; d2[i] = ||goal[i]-position[i]||;
// new_h[i][j] = sigmoid(C[j] + d2[i]*Wd[j] + dot(h[i], W2[j][:])), W2[j][k]=W_fc[j][64+k].
// h_out[idx] = h[idx]. goal_out (64) computed once.
//
// R12: nontemporal dense stores. Ten configs (R4-R11: occupancy 8-32 w/CU,
// prefetch depth 1-4, fragment vs dense VMEM, fwd/rev sweep, store-drain vs
// no-drain) all pin TOTAL fabric throughput at 3.0-3.3 TB/s -- the cap is on
// the service side, not wave-side latency/concurrency. Last untested
// difference vs the 6.3 TB/s copy ceiling: our 128 MB write-once stream
// pollutes L2/L3 (dirty-line allocation + writeback evicts the h lines that
// cross-dispatch retention feeds on). R3's nt attempt failed only because it
// paired nt with 64-B scattered stores (partial lines -> RMW). R10/R11
// stores are DENSE (1KB/instr, full 128B lines), so nt is now safe: writes
// stream past the caches, L2/L3 serve the read stream only. Single-lever
// change on R11: the 4 output stores -> __builtin_nontemporal_store.

#define AH 64
#define AD 32

typedef __attribute__((ext_vector_type(8))) short bf16x8;
typedef __attribute__((ext_vector_type(4))) float f32x4;
typedef __attribute__((ext_vector_type(2))) float f32x2;

__device__ __forceinline__ float sigmoid_fast(float x) {
    return __builtin_amdgcn_rcpf(1.0f + __expf(-x));
}

__device__ __forceinline__ short f2bf(float f) {
    union { float f; unsigned u; } v; v.f = f;
    unsigned r = v.u + 0x7fffu + ((v.u >> 16) & 1u);
    return (short)(r >> 16);
}

// ws layout (floats): [0:64) C, [64:128) Wd, [128:2176) = bf16x8 wfrag[8][64],
// [2176] (as int) = launch counter for sweep direction.
__global__ void ig_precompute(
    const float* __restrict__ h,      // N x 64
    const float* __restrict__ ghs,    // 64
    const float* __restrict__ goal,   // N x 2
    const float* __restrict__ pos,    // N x 2
    const float* __restrict__ W_emb,  // 32 x 2
    const float* __restrict__ b_emb,  // 32
    const float* __restrict__ W_fc,   // 64 x 192
    const float* __restrict__ b_fc,   // 64
    const int*   __restrict__ idx_p,
    float* __restrict__ out_goal,     // 64
    float* __restrict__ ws,
    int*   flip)                      // may be null
{
    const int l = threadIdx.x;        // 0..63
    if (l >= 64) return;
    const int idx = idx_p[0];
    const int m15 = l & 15, q = l >> 4;

    if (l == 0 && flip) flip[0] = flip[0] + 1;   // alternates sweep direction

    // --- C[l], Wd[l], goal_out[l] ---
    const float* wrow = W_fc + l * 192;
    const f32x4* w4  = (const f32x4*)wrow;
    const f32x4* wg4 = (const f32x4*)(wrow + AH);
    const f32x4* h4  = (const f32x4*)(h + (size_t)idx * AH);
    const f32x4* g4  = (const f32x4*)ghs;
    float c = b_fc[l], g = b_fc[l];
    #pragma unroll
    for (int m = 0; m < 16; ++m) {
        const f32x4 hv = h4[m], wv = w4[m];
        const float d = hv[0]*wv[0] + hv[1]*wv[1] + hv[2]*wv[2] + hv[3]*wv[3];
        c += d; g += d;
        const f32x4 gv = g4[m], wv2 = wg4[m];
        g += gv[0]*wv2[0] + gv[1]*wv2[1] + gv[2]*wv2[2] + gv[3]*wv2[3];
    }
    const float px = pos[(size_t)idx*2+0], py = pos[(size_t)idx*2+1];
    const float gx = goal[(size_t)idx*2+0], gy = goal[(size_t)idx*2+1];
    const float dgx = px - gx, dgy = py - gy;
    const float dg = sqrtf(dgx*dgx + dgy*dgy);
    const float* wd1 = wrow + 128;
    const float* wd2 = wrow + 160;
    float wd = 0.f;
    #pragma unroll
    for (int k = 0; k < AD; ++k) {
        const float wsum = W_emb[2*k] + W_emb[2*k+1];
        const float be   = b_emb[k];
        const float w12  = wd1[k] + wd2[k];
        c  += be * w12;
        wd += wsum * wd2[k];
        g  += (dg * wsum + be) * w12;
    }
    ws[l]      = c;
    ws[64 + l] = wd;
    out_goal[l] = sigmoid_fast(g);

    // --- weight A-frags: wfrag[f=mg*2+cc][lane] = W2[mg*16+m15][cc*32+q*8 .. +7] ---
    bf16x8* wf = (bf16x8*)(ws + 128);
    #pragma unroll
    for (int f = 0; f < 8; ++f) {
        const int mg = f >> 1, cc = f & 1;
        const float* src = W_fc + (size_t)(mg*16 + m15) * 192 + AH + cc*32 + q*8;
        const f32x4 s0 = *(const f32x4*)(src);
        const f32x4 s1 = *(const f32x4*)(src + 4);
        bf16x8 b;
        #pragma unroll
        for (int j = 0; j < 4; ++j) { b[j] = f2bf(s0[j]); b[4+j] = f2bf(s1[j]); }
        wf[f * 64 + l] = b;
    }
}

__global__ __launch_bounds__(256, 4) void ig_main(
    const float* __restrict__ h,      // N x 64
    const float* __restrict__ goal,   // N x 2
    const float* __restrict__ pos,    // N x 2
    const float* __restrict__ ws,     // C, Wd, wfrag
    const int*   __restrict__ idx_p,
    const int*   __restrict__ flip,   // may be null
    float* __restrict__ out,          // N x 64
    int n_tiles, int total_waves)
{
    __shared__ bf16x8 wlds[8][64];               // 8 KB (weight frags)
    __shared__ __align__(16) float cw[128];      // C, Wd
    __shared__ __align__(16) float tbuf[4][1024];// per-wave 4KB tile buffer

    const int tid  = threadIdx.x;
    const int w    = tid >> 6;
    const int lane = tid & 63;
    const int m15  = lane & 15;
    const int q    = lane >> 4;
    const int idx  = idx_p[0];
    const int dir  = flip ? (flip[0] & 1) : 0;   // wave-uniform
    const int nt1  = n_tiles - 1;

    // idx-tile bookkeeping (wave-uniform scalars + one per-lane mask).
    const int idx_tile = idx >> 4;               // tile containing row idx
    const int idx_r    = idx & 15;               // row within that tile
    const int idx_k    = idx_r >> 2;             // register quarter holding it
    const bool idx_lane = ((lane >> 4) == (idx_r & 3)); // lanes covering the row

    // Stage ws -> LDS: 128 floats + 512 x 16B chunks.
    if (tid < 128) cw[tid] = ws[tid];
    {
        const f32x4* src = (const f32x4*)(ws + 128);
        f32x4* dst = (f32x4*)wlds;
        dst[tid]       = src[tid];
        dst[tid + 256] = src[tid + 256];
    }
    __syncthreads();

    float* tb = tbuf[w];                         // this wave's private buffer

    // Loop-invariant LDS float-offsets. Tile = 16 rows x 16 chunks (16B each);
    // chunk (r,c) lives at float offset (r*16 + (c ^ (r&7))) * 4.
    int stg0, stg1, stg2, stg3;
    {
        const int r0 = 0*4 + (lane >> 4), c = lane & 15;
        const int r1 = r0 + 4, r2 = r0 + 8, r3 = r0 + 12;
        stg0 = (r0*16 + (c ^ (r0 & 7))) * 4;
        stg1 = (r1*16 + (c ^ (r1 & 7))) * 4;
        stg2 = (r2*16 + (c ^ (r2 & 7))) * 4;
        stg3 = (r3*16 + (c ^ (r3 & 7))) * 4;
    }
    const int e = m15 & 7;
    // MFMA fragment chunks: row m15, chunks {2q,2q+1,8+2q,9+2q}.
    const int fb0 = (m15*16 + ((2*q)     ^ e)) * 4;
    const int fb1 = (m15*16 + ((2*q + 1) ^ e)) * 4;
    const int fb2 = (m15*16 + ((8 + 2*q) ^ e)) * 4;
    const int fb3 = (m15*16 + ((9 + 2*q) ^ e)) * 4;
    // Result chunks: row m15, chunk mg*4+q (floats mg*16+q*4 .. +3).
    const int ow0 = (m15*16 + ((0*4 + q) ^ e)) * 4;
    const int ow1 = (m15*16 + ((1*4 + q) ^ e)) * 4;
    const int ow2 = (m15*16 + ((2*4 + q) ^ e)) * 4;
    const int ow3 = (m15*16 + ((3*4 + q) ^ e)) * 4;

    const int wid = blockIdx.x * 4 + w;
    const int TW  = total_waves;                 // 4096

    // Depth-1 pipeline: tile t's 4KB is in regs G0..G3 (dense layout:
    // Gk = tile bytes [k*1024 + lane*16, +16) ), goal/pos in gv/pv.
    int t = wid;                                 // wid < 4096 <= n_tiles
    f32x4 G0, G1, G2, G3; f32x2 gv, pv;
    {
        const int mt = dir ? nt1 - t : t;
        const float* hb = h + (size_t)mt * 1024;
        G0 = *(const f32x4*)(hb +   0 + lane*4);
        G1 = *(const f32x4*)(hb + 256 + lane*4);
        G2 = *(const f32x4*)(hb + 512 + lane*4);
        G3 = *(const f32x4*)(hb + 768 + lane*4);
        const int nn = mt*16 + m15;
        gv = *(const f32x2*)(goal + 2*(size_t)nn);
        pv = *(const f32x2*)(pos  + 2*(size_t)nn);
    }

    while (t < n_tiles) {
        // Dense prefetch of next tile (shared row-0 clamp past end: one 4KB
        // region for ALL waves -> L2-hot, ~free). Issued before anything
        // else so later waitcnts never drain this iteration's stores.
        const int tn  = t + TW;
        const int mtn = (tn < n_tiles) ? (dir ? nt1 - tn : tn) : 0;
        f32x4 N0, N1, N2, N3; f32x2 ngv, npv;
        {
            const float* hb = h + (size_t)mtn * 1024;
            N0 = *(const f32x4*)(hb +   0 + lane*4);
            N1 = *(const f32x4*)(hb + 256 + lane*4);
            N2 = *(const f32x4*)(hb + 512 + lane*4);
            N3 = *(const f32x4*)(hb + 768 + lane*4);
            const int nn = mtn*16 + m15;
            ngv = *(const f32x2*)(goal + 2*(size_t)nn);
            npv = *(const f32x2*)(pos  + 2*(size_t)nn);
        }

        // Stage current tile into LDS (waits only on last iter's loads,
        // which have had a full iteration to complete).
        *(f32x4*)(tb + stg0) = G0;
        *(f32x4*)(tb + stg1) = G1;
        *(f32x4*)(tb + stg2) = G2;
        *(f32x4*)(tb + stg3) = G3;

        // Read MFMA fragments (in-order DS per wave; compiler inserts lgkm).
        const f32x4 b0 = *(const f32x4*)(tb + fb0);
        const f32x4 b1 = *(const f32x4*)(tb + fb1);
        const f32x4 b2 = *(const f32x4*)(tb + fb2);
        const f32x4 b3 = *(const f32x4*)(tb + fb3);

        const int mt = dir ? nt1 - t : t;
        const float dx = gv[0] - pv[0], dy = gv[1] - pv[1];
        const float d2v = sqrtf(dx*dx + dy*dy);

        bf16x8 bf0, bf1;
        #pragma unroll
        for (int j = 0; j < 4; ++j) {
            bf0[j] = f2bf(b0[j]); bf0[4+j] = f2bf(b1[j]);
            bf1[j] = f2bf(b2[j]); bf1[4+j] = f2bf(b3[j]);
        }

        #pragma unroll
        for (int mg = 0; mg < 4; ++mg) {
            const f32x4 c4 = *(const f32x4*)&cw[mg*16 + q*4];
            const f32x4 d4 = *(const f32x4*)&cw[64 + mg*16 + q*4];
            f32x4 acc;
            #pragma unroll
            for (int r = 0; r < 4; ++r) acc[r] = c4[r] + d2v * d4[r];
            acc = __builtin_amdgcn_mfma_f32_16x16x32_bf16(wlds[mg*2+0][lane], bf0, acc, 0, 0, 0);
            acc = __builtin_amdgcn_mfma_f32_16x16x32_bf16(wlds[mg*2+1][lane], bf1, acc, 0, 0, 0);

            f32x4 vv;
            #pragma unroll
            for (int r = 0; r < 4; ++r) vv[r] = sigmoid_fast(acc[r]);
            const int owx = (mg == 0) ? ow0 : (mg == 1) ? ow1 : (mg == 2) ? ow2 : ow3;
            *(f32x4*)(tb + owx) = vv;            // LDS result write (swizzled)
        }

        // Dense read-back.
        f32x4 S0 = *(const f32x4*)(tb + stg0);
        f32x4 S1 = *(const f32x4*)(tb + stg1);
        f32x4 S2 = *(const f32x4*)(tb + stg2);
        f32x4 S3 = *(const f32x4*)(tb + stg3);

        // h_out[idx] = h[idx]: the needed bytes are ALREADY in G_k for the
        // owning tile. Wave-uniform branch (taken by 1 wave in 8192), pure
        // VALU blend -- no loads, so stores keep zero VMEM dependencies.
        if (mt == idx_tile) {
            if (idx_lane) {
                if (idx_k == 0) S0 = G0;
                else if (idx_k == 1) S1 = G1;
                else if (idx_k == 2) S2 = G2;
                else S3 = G3;
            }
        }

        // Dense NONTEMPORAL global store: 1KB/instr, full 128B lines (no
        // RMW possible), streams past L2/L3 so the caches serve reads only.
        float* ob = out + (size_t)mt * 1024;
        __builtin_nontemporal_store(S0, (f32x4*)(ob +   0 + lane*4));
        __builtin_nontemporal_store(S1, (f32x4*)(ob + 256 + lane*4));
        __builtin_nontemporal_store(S2, (f32x4*)(ob + 512 + lane*4));
        __builtin_nontemporal_store(S3, (f32x4*)(ob + 768 + lane*4));

        t = tn;
        G0 = N0; G1 = N1; G2 = N2; G3 = N3; gv = ngv; pv = npv;
    }
}

extern "C" void kernel_launch(void* const* d_in, const int* in_sizes, int n_in,
                              void* d_out, int out_size, void* d_ws, size_t ws_size,
                              hipStream_t stream) {
    const float* h     = (const float*)d_in[0];
    const float* ghs   = (const float*)d_in[1];
    const float* goal  = (const float*)d_in[2];
    const float* pos   = (const float*)d_in[3];
    const float* W_emb = (const float*)d_in[4];
    const float* b_emb = (const float*)d_in[5];
    const float* W_fc  = (const float*)d_in[6];
    const float* b_fc  = (const float*)d_in[7];
    const int*   idx_p = (const int*)d_in[8];

    const int N = in_sizes[0] / AH;          // 500000
    float* out      = (float*)d_out;
    float* out_goal = out + (size_t)N * AH;
    float* ws       = (float*)d_ws;          // 128 + 2048 floats + counter
    int*   flip     = (ws_size >= 2177u * 4u) ? ((int*)d_ws) + 2176 : (int*)0;

    ig_precompute<<<1, 64, 0, stream>>>(h, ghs, goal, pos, W_emb, b_emb, W_fc, b_fc,
                                        idx_p, out_goal, ws, flip);

    const int n_tiles = N / 16;              // 31250
    const int blocks = 1024;                 // 4 blocks/CU (LDS 24.5KB/block)
    const int total_waves = blocks * 4;      // TW = 4096
    ig_main<<<blocks, 256, 0, stream>>>(h, goal, pos, ws, idx_p, flip, out,
                                        n_tiles, total_waves);
}